// Round 1
// baseline (615.086 us; speedup 1.0000x reference)
//
#include <hip/hip_runtime.h>
#include <hip/hip_bf16.h>
#include <stdint.h>

// SelfAttention: out = softmax((x Wq^T)(x Wk^T)^T / sqrt(D)) (x Wv^T)
// SEQ=8192, D=1024, fp32 in/out. All GEMMs in bf16 MFMA (error analysis:
// ~1e-4 max vs 1e-3 threshold).
//
// Workspace layout (needs ~198 MB):
//   [0)        x_bf16 16MB   (reused as v^T after v GEMM — x dead by then)
//   [16MB)     Wq/Wk/Wv bf16 2MB each
//   [22MB)     q bf16 16MB
//   [38MB)     k bf16 16MB
//   [54MB)     v bf16 16MB
//   [70MB)     S/P bf16 128MB (scores, softmaxed in place)

#define SEQ 8192
#define DMODEL 1024
#define LOG2E 1.44269504088896340736f

typedef __bf16 bf16_t;
typedef __bf16 bf16x8 __attribute__((ext_vector_type(8)));
typedef float f32x4 __attribute__((ext_vector_type(4)));

// ---------------- fp32 -> bf16 convert ----------------
__global__ __launch_bounds__(256)
void convert_f32_bf16(const float* __restrict__ in, bf16_t* __restrict__ out, long n) {
    long i = ((long)blockIdx.x * 256 + threadIdx.x) * 4;
    if (i + 3 < n) {
        const float4 v = *(const float4*)(in + i);
        union { ushort4 u; bf16_t b[4]; } p;
        p.b[0] = (bf16_t)v.x; p.b[1] = (bf16_t)v.y;
        p.b[2] = (bf16_t)v.z; p.b[3] = (bf16_t)v.w;
        *(ushort4*)(out + i) = p.u;
    }
}

// ---------------- NT GEMM: C[M,N] = alpha * A[M,K] @ B[N,K]^T ----------------
// m97-style: 128x128 tile, BK=32, 256 threads (4 waves, 2x2), each wave 64x64
// via 4x4 grid of mfma_f32_16x16x32_bf16. global_load_lds width-16 staging
// (LDS dest = wave-uniform base + lane*16, so LDS tile is unpadded [128][32]).
template <typename OutT>
__global__ __launch_bounds__(256, 3)
void gemm_nt(const bf16_t* __restrict__ A, const bf16_t* __restrict__ B,
             OutT* __restrict__ C, int M, int N, int K, float alpha)
{
    __shared__ bf16_t As[128 * 32];
    __shared__ bf16_t Bs[128 * 32];

    const int tid  = threadIdx.x;
    const int wave = tid >> 6;
    const int lane = tid & 63;
    const long row0 = (long)blockIdx.y * 128;
    const long col0 = (long)blockIdx.x * 128;

    const int wm = (wave >> 1) * 64;   // wave's 64x64 sub-tile
    const int wn = (wave & 1) * 64;
    const int lr = lane & 15;          // fragment non-K index
    const int lq = lane >> 4;          // quad 0..3 -> k-chunk / row group

    f32x4 acc[4][4] = {};

    for (int k0 = 0; k0 < K; k0 += 32) {
        // Stage A,B 128x32 tiles: 512 chunks of 16B each; chunk c -> row c>>2,
        // col-chunk c&3. Wave w issue i covers chunks [i*256+w*64, +64).
        #pragma unroll
        for (int i = 0; i < 2; ++i) {
            const int cbase = i * 256 + wave * 64;
            const int c = cbase + lane;
            const int r = c >> 2, cc = c & 3;
            const bf16_t* ga = A + (row0 + r) * (long)K + k0 + cc * 8;
            const bf16_t* gb = B + (col0 + r) * (long)K + k0 + cc * 8;
            __builtin_amdgcn_global_load_lds(
                (const __attribute__((address_space(1))) uint32_t*)ga,
                (__attribute__((address_space(3))) uint32_t*)(As + (long)cbase * 8),
                16, 0, 0);
            __builtin_amdgcn_global_load_lds(
                (const __attribute__((address_space(1))) uint32_t*)gb,
                (__attribute__((address_space(3))) uint32_t*)(Bs + (long)cbase * 8),
                16, 0, 0);
        }
        __syncthreads();

        bf16x8 af[4], bfr[4];
        #pragma unroll
        for (int mi = 0; mi < 4; ++mi)
            af[mi] = *(const bf16x8*)(As + (wm + mi * 16 + lr) * 32 + lq * 8);
        #pragma unroll
        for (int ni = 0; ni < 4; ++ni)
            bfr[ni] = *(const bf16x8*)(Bs + (wn + ni * 16 + lr) * 32 + lq * 8);

        #pragma unroll
        for (int mi = 0; mi < 4; ++mi)
            #pragma unroll
            for (int ni = 0; ni < 4; ++ni)
                acc[mi][ni] = __builtin_amdgcn_mfma_f32_16x16x32_bf16(
                    af[mi], bfr[ni], acc[mi][ni], 0, 0, 0);
        __syncthreads();
    }

    // Epilogue: C/D layout col=lane&15, row=(lane>>4)*4+reg  [m89/m91 verified]
    #pragma unroll
    for (int mi = 0; mi < 4; ++mi)
        #pragma unroll
        for (int ni = 0; ni < 4; ++ni)
            #pragma unroll
            for (int rg = 0; rg < 4; ++rg) {
                const long r = row0 + wm + mi * 16 + lq * 4 + rg;
                const long c = col0 + wn + ni * 16 + lr;
                C[r * (long)N + c] = (OutT)(alpha * acc[mi][ni][rg]);
            }
}

// ---------------- bf16 transpose (v -> v^T so PV GEMM is NT) ----------------
__global__ __launch_bounds__(256)
void transpose_bf16(const bf16_t* __restrict__ in, bf16_t* __restrict__ out,
                    int R, int Ccols)
{
    __shared__ bf16_t tile[32][33];
    const int tx = threadIdx.x & 31;
    const int ty = threadIdx.x >> 5;   // 0..7
    const int c0 = blockIdx.x * 32;
    const int r0 = blockIdx.y * 32;
    #pragma unroll
    for (int j = 0; j < 32; j += 8)
        tile[ty + j][tx] = in[(long)(r0 + ty + j) * Ccols + c0 + tx];
    __syncthreads();
    #pragma unroll
    for (int j = 0; j < 32; j += 8)
        out[(long)(c0 + ty + j) * R + r0 + tx] = tile[tx][ty + j];
}

// ---------------- row softmax over bf16 [SEQ, SEQ], in place ----------------
__global__ __launch_bounds__(256)
void softmax_rows(bf16_t* __restrict__ S, int n)
{
    const long row = blockIdx.x;
    bf16_t* p = S + row * (long)n;
    const int tid = threadIdx.x;
    const int wave = tid >> 6, lane = tid & 63;
    __shared__ float red[4];

    float v[32];
    #pragma unroll
    for (int j = 0; j < 4; ++j) {
        bf16x8 x = *(const bf16x8*)(p + ((long)(j * 256 + tid)) * 8);
        #pragma unroll
        for (int e = 0; e < 8; ++e) v[j * 8 + e] = (float)x[e];
    }
    float m = -3.4e38f;
    #pragma unroll
    for (int i = 0; i < 32; ++i) m = fmaxf(m, v[i]);
    #pragma unroll
    for (int off = 32; off > 0; off >>= 1) m = fmaxf(m, __shfl_xor(m, off));
    if (lane == 0) red[wave] = m;
    __syncthreads();
    m = fmaxf(fmaxf(red[0], red[1]), fmaxf(red[2], red[3]));
    __syncthreads();

    float s = 0.f;
    #pragma unroll
    for (int i = 0; i < 32; ++i) { v[i] = exp2f((v[i] - m) * LOG2E); s += v[i]; }
    #pragma unroll
    for (int off = 32; off > 0; off >>= 1) s += __shfl_xor(s, off);
    if (lane == 0) red[wave] = s;
    __syncthreads();
    s = red[0] + red[1] + red[2] + red[3];
    const float inv = 1.f / s;

    #pragma unroll
    for (int j = 0; j < 4; ++j) {
        bf16x8 x;
        #pragma unroll
        for (int e = 0; e < 8; ++e) x[e] = (bf16_t)(v[j * 8 + e] * inv);
        *(bf16x8*)(p + ((long)(j * 256 + tid)) * 8) = x;
    }
}

extern "C" void kernel_launch(void* const* d_in, const int* in_sizes, int n_in,
                              void* d_out, int out_size, void* d_ws, size_t ws_size,
                              hipStream_t stream)
{
    const float* x  = (const float*)d_in[0];
    const float* Wq = (const float*)d_in[1];
    const float* Wk = (const float*)d_in[2];
    const float* Wv = (const float*)d_in[3];
    float* out = (float*)d_out;

    char* ws = (char*)d_ws;
    const long XN = (long)SEQ * DMODEL;     // 8,388,608
    const long WN = (long)DMODEL * DMODEL;  // 1,048,576

    bf16_t* xb  = (bf16_t*)ws;                                   // 16MB
    bf16_t* wqb = (bf16_t*)(ws + XN * 2);                        // 2MB
    bf16_t* wkb = (bf16_t*)(ws + XN * 2 + WN * 2);               // 2MB
    bf16_t* wvb = (bf16_t*)(ws + XN * 2 + WN * 4);               // 2MB
    bf16_t* qb  = (bf16_t*)(ws + XN * 2 + WN * 6);               // 16MB
    bf16_t* kb  = (bf16_t*)(ws + XN * 2 + WN * 6 + XN * 2);      // 16MB
    bf16_t* vb  = (bf16_t*)(ws + XN * 2 + WN * 6 + XN * 4);      // 16MB
    bf16_t* Sb  = (bf16_t*)(ws + XN * 2 + WN * 6 + XN * 6);      // 128MB
    bf16_t* vtb = xb;  // v^T overlays x_bf16 (x dead after v GEMM)

    convert_f32_bf16<<<(int)(XN / 4 / 256), 256, 0, stream>>>(x,  xb,  XN);
    convert_f32_bf16<<<(int)(WN / 4 / 256), 256, 0, stream>>>(Wq, wqb, WN);
    convert_f32_bf16<<<(int)(WN / 4 / 256), 256, 0, stream>>>(Wk, wkb, WN);
    convert_f32_bf16<<<(int)(WN / 4 / 256), 256, 0, stream>>>(Wv, wvb, WN);

    dim3 blk(256);
    // q,k,v = x @ W^T   (NT: both K-contiguous)
    gemm_nt<bf16_t><<<dim3(DMODEL / 128, SEQ / 128), blk, 0, stream>>>(
        xb, wqb, qb, SEQ, DMODEL, DMODEL, 1.0f);
    gemm_nt<bf16_t><<<dim3(DMODEL / 128, SEQ / 128), blk, 0, stream>>>(
        xb, wkb, kb, SEQ, DMODEL, DMODEL, 1.0f);
    gemm_nt<bf16_t><<<dim3(DMODEL / 128, SEQ / 128), blk, 0, stream>>>(
        xb, wvb, vb, SEQ, DMODEL, DMODEL, 1.0f);

    // v^T for the PV GEMM (writes over dead x_bf16)
    transpose_bf16<<<dim3(DMODEL / 32, SEQ / 32), blk, 0, stream>>>(
        vb, vtb, SEQ, DMODEL);

    // S = (q @ k^T) * 1/sqrt(1024)
    gemm_nt<bf16_t><<<dim3(SEQ / 128, SEQ / 128), blk, 0, stream>>>(
        qb, kb, Sb, SEQ, SEQ, DMODEL, 0.03125f);

    softmax_rows<<<SEQ, blk, 0, stream>>>(Sb, SEQ);

    // out = P @ v = P @ (v^T)^T  (NT, fp32 output)
    gemm_nt<float><<<dim3(DMODEL / 128, SEQ / 128), blk, 0, stream>>>(
        Sb, vtb, out, SEQ, DMODEL, SEQ, 1.0f);
}

// Round 2
// 574.645 us; speedup vs baseline: 1.0704x; 1.0704x over previous
//
#include <hip/hip_runtime.h>
#include <hip/hip_bf16.h>
#include <stdint.h>

// SelfAttention: out = softmax((x Wq^T)(x Wk^T)^T / sqrt(D)) (x Wv^T)
// SEQ=8192, D=1024, fp32 in/out. All GEMMs in bf16 MFMA.
// R2: grouped block swizzle (GROUP_M=8) for L2/L3 locality in the S-GEMM
// (R1 showed it HBM-bound: FETCH 800MB vs 32MB ideal, 3.4 TB/s, MfmaUtil 23%).

#define SEQ 8192
#define DMODEL 1024
#define LOG2E 1.44269504088896340736f

typedef __bf16 bf16_t;
typedef __bf16 bf16x8 __attribute__((ext_vector_type(8)));
typedef float f32x4 __attribute__((ext_vector_type(4)));

// ---------------- fp32 -> bf16 convert ----------------
__global__ __launch_bounds__(256)
void convert_f32_bf16(const float* __restrict__ in, bf16_t* __restrict__ out, long n) {
    long i = ((long)blockIdx.x * 256 + threadIdx.x) * 4;
    if (i + 3 < n) {
        const float4 v = *(const float4*)(in + i);
        union { ushort4 u; bf16_t b[4]; } p;
        p.b[0] = (bf16_t)v.x; p.b[1] = (bf16_t)v.y;
        p.b[2] = (bf16_t)v.z; p.b[3] = (bf16_t)v.w;
        *(ushort4*)(out + i) = p.u;
    }
}

// ---------------- NT GEMM: C[M,N] = alpha * A[M,K] @ B[N,K]^T ----------------
// 128x128 tile, BK=32, 256 threads (4 waves, 2x2), each wave 64x64 via 4x4
// grid of mfma_f32_16x16x32_bf16. global_load_lds width-16 staging.
// Flat 1D grid + grouped swizzle: groups of GROUP_M row-tiles iterated
// col-major inside, so concurrent blocks share q-rows AND k-cols in L2/L3.
#define GROUP_M 8
template <typename OutT>
__global__ __launch_bounds__(256, 3)
void gemm_nt(const bf16_t* __restrict__ A, const bf16_t* __restrict__ B,
             OutT* __restrict__ C, int M, int N, int K, float alpha)
{
    __shared__ bf16_t As[128 * 32];
    __shared__ bf16_t Bs[128 * 32];

    const int tid  = threadIdx.x;
    const int wave = tid >> 6;
    const int lane = tid & 63;

    // grouped swizzle
    const int nbm = M >> 7, nbn = N >> 7;
    const int per_group = GROUP_M * nbn;
    const int gid   = blockIdx.x / per_group;
    const int rem   = blockIdx.x - gid * per_group;
    const int first = gid * GROUP_M;
    const int gsz   = min(nbm - first, GROUP_M);
    const int bm    = first + rem % gsz;
    const int bn    = rem / gsz;
    const long row0 = (long)bm * 128;
    const long col0 = (long)bn * 128;

    const int wm = (wave >> 1) * 64;   // wave's 64x64 sub-tile
    const int wn = (wave & 1) * 64;
    const int lr = lane & 15;          // fragment non-K index
    const int lq = lane >> 4;          // quad 0..3 -> k-chunk / row group

    f32x4 acc[4][4] = {};

    for (int k0 = 0; k0 < K; k0 += 32) {
        // Stage A,B 128x32 tiles: 512 chunks of 16B; chunk c -> row c>>2,
        // col-chunk c&3. Wave w issue i covers chunks [i*256+w*64, +64).
        #pragma unroll
        for (int i = 0; i < 2; ++i) {
            const int cbase = i * 256 + wave * 64;
            const int c = cbase + lane;
            const int r = c >> 2, cc = c & 3;
            const bf16_t* ga = A + (row0 + r) * (long)K + k0 + cc * 8;
            const bf16_t* gb = B + (col0 + r) * (long)K + k0 + cc * 8;
            __builtin_amdgcn_global_load_lds(
                (const __attribute__((address_space(1))) uint32_t*)ga,
                (__attribute__((address_space(3))) uint32_t*)(As + (long)cbase * 8),
                16, 0, 0);
            __builtin_amdgcn_global_load_lds(
                (const __attribute__((address_space(1))) uint32_t*)gb,
                (__attribute__((address_space(3))) uint32_t*)(Bs + (long)cbase * 8),
                16, 0, 0);
        }
        __syncthreads();

        bf16x8 af[4], bfr[4];
        #pragma unroll
        for (int mi = 0; mi < 4; ++mi)
            af[mi] = *(const bf16x8*)(As + (wm + mi * 16 + lr) * 32 + lq * 8);
        #pragma unroll
        for (int ni = 0; ni < 4; ++ni)
            bfr[ni] = *(const bf16x8*)(Bs + (wn + ni * 16 + lr) * 32 + lq * 8);

        #pragma unroll
        for (int mi = 0; mi < 4; ++mi)
            #pragma unroll
            for (int ni = 0; ni < 4; ++ni)
                acc[mi][ni] = __builtin_amdgcn_mfma_f32_16x16x32_bf16(
                    af[mi], bfr[ni], acc[mi][ni], 0, 0, 0);
        __syncthreads();
    }

    // Epilogue: C/D layout col=lane&15, row=(lane>>4)*4+reg  [m89/m91 verified]
    #pragma unroll
    for (int mi = 0; mi < 4; ++mi)
        #pragma unroll
        for (int ni = 0; ni < 4; ++ni)
            #pragma unroll
            for (int rg = 0; rg < 4; ++rg) {
                const long r = row0 + wm + mi * 16 + lq * 4 + rg;
                const long c = col0 + wn + ni * 16 + lr;
                C[r * (long)N + c] = (OutT)(alpha * acc[mi][ni][rg]);
            }
}

// ---------------- bf16 transpose (v -> v^T so PV GEMM is NT) ----------------
__global__ __launch_bounds__(256)
void transpose_bf16(const bf16_t* __restrict__ in, bf16_t* __restrict__ out,
                    int R, int Ccols)
{
    __shared__ bf16_t tile[32][33];
    const int tx = threadIdx.x & 31;
    const int ty = threadIdx.x >> 5;   // 0..7
    const int c0 = blockIdx.x * 32;
    const int r0 = blockIdx.y * 32;
    #pragma unroll
    for (int j = 0; j < 32; j += 8)
        tile[ty + j][tx] = in[(long)(r0 + ty + j) * Ccols + c0 + tx];
    __syncthreads();
    #pragma unroll
    for (int j = 0; j < 32; j += 8)
        out[(long)(c0 + ty + j) * R + r0 + tx] = tile[tx][ty + j];
}

// ---------------- row softmax over bf16 [SEQ, SEQ], in place ----------------
__global__ __launch_bounds__(256)
void softmax_rows(bf16_t* __restrict__ S, int n)
{
    const long row = blockIdx.x;
    bf16_t* p = S + row * (long)n;
    const int tid = threadIdx.x;
    const int wave = tid >> 6, lane = tid & 63;
    __shared__ float red[4];

    float v[32];
    #pragma unroll
    for (int j = 0; j < 4; ++j) {
        bf16x8 x = *(const bf16x8*)(p + ((long)(j * 256 + tid)) * 8);
        #pragma unroll
        for (int e = 0; e < 8; ++e) v[j * 8 + e] = (float)x[e];
    }
    float m = -3.4e38f;
    #pragma unroll
    for (int i = 0; i < 32; ++i) m = fmaxf(m, v[i]);
    #pragma unroll
    for (int off = 32; off > 0; off >>= 1) m = fmaxf(m, __shfl_xor(m, off));
    if (lane == 0) red[wave] = m;
    __syncthreads();
    m = fmaxf(fmaxf(red[0], red[1]), fmaxf(red[2], red[3]));
    __syncthreads();

    float s = 0.f;
    #pragma unroll
    for (int i = 0; i < 32; ++i) { v[i] = exp2f((v[i] - m) * LOG2E); s += v[i]; }
    #pragma unroll
    for (int off = 32; off > 0; off >>= 1) s += __shfl_xor(s, off);
    if (lane == 0) red[wave] = s;
    __syncthreads();
    s = red[0] + red[1] + red[2] + red[3];
    const float inv = 1.f / s;

    #pragma unroll
    for (int j = 0; j < 4; ++j) {
        bf16x8 x;
        #pragma unroll
        for (int e = 0; e < 8; ++e) x[e] = (bf16_t)(v[j * 8 + e] * inv);
        *(bf16x8*)(p + ((long)(j * 256 + tid)) * 8) = x;
    }
}

extern "C" void kernel_launch(void* const* d_in, const int* in_sizes, int n_in,
                              void* d_out, int out_size, void* d_ws, size_t ws_size,
                              hipStream_t stream)
{
    const float* x  = (const float*)d_in[0];
    const float* Wq = (const float*)d_in[1];
    const float* Wk = (const float*)d_in[2];
    const float* Wv = (const float*)d_in[3];
    float* out = (float*)d_out;

    char* ws = (char*)d_ws;
    const long XN = (long)SEQ * DMODEL;     // 8,388,608
    const long WN = (long)DMODEL * DMODEL;  // 1,048,576

    bf16_t* xb  = (bf16_t*)ws;                                   // 16MB
    bf16_t* wqb = (bf16_t*)(ws + XN * 2);                        // 2MB
    bf16_t* wkb = (bf16_t*)(ws + XN * 2 + WN * 2);               // 2MB
    bf16_t* wvb = (bf16_t*)(ws + XN * 2 + WN * 4);               // 2MB
    bf16_t* qb  = (bf16_t*)(ws + XN * 2 + WN * 6);               // 16MB
    bf16_t* kb  = (bf16_t*)(ws + XN * 2 + WN * 6 + XN * 2);      // 16MB
    bf16_t* vb  = (bf16_t*)(ws + XN * 2 + WN * 6 + XN * 4);      // 16MB
    bf16_t* Sb  = (bf16_t*)(ws + XN * 2 + WN * 6 + XN * 6);      // 128MB
    bf16_t* vtb = xb;  // v^T overlays x_bf16 (x dead after v GEMM)

    convert_f32_bf16<<<(int)(XN / 4 / 256), 256, 0, stream>>>(x,  xb,  XN);
    convert_f32_bf16<<<(int)(WN / 4 / 256), 256, 0, stream>>>(Wq, wqb, WN);
    convert_f32_bf16<<<(int)(WN / 4 / 256), 256, 0, stream>>>(Wk, wkb, WN);
    convert_f32_bf16<<<(int)(WN / 4 / 256), 256, 0, stream>>>(Wv, wvb, WN);

    dim3 blk(256);
    // q,k,v = x @ W^T   (NT: both K-contiguous). Grid flat: (M/128)*(N/128).
    gemm_nt<bf16_t><<<(SEQ / 128) * (DMODEL / 128), blk, 0, stream>>>(
        xb, wqb, qb, SEQ, DMODEL, DMODEL, 1.0f);
    gemm_nt<bf16_t><<<(SEQ / 128) * (DMODEL / 128), blk, 0, stream>>>(
        xb, wkb, kb, SEQ, DMODEL, DMODEL, 1.0f);
    gemm_nt<bf16_t><<<(SEQ / 128) * (DMODEL / 128), blk, 0, stream>>>(
        xb, wvb, vb, SEQ, DMODEL, DMODEL, 1.0f);

    // v^T for the PV GEMM (writes over dead x_bf16)
    transpose_bf16<<<dim3(DMODEL / 32, SEQ / 32), blk, 0, stream>>>(
        vb, vtb, SEQ, DMODEL);

    // S = (q @ k^T) * 1/sqrt(1024)
    gemm_nt<bf16_t><<<(SEQ / 128) * (SEQ / 128), blk, 0, stream>>>(
        qb, kb, Sb, SEQ, SEQ, DMODEL, 0.03125f);

    softmax_rows<<<SEQ, blk, 0, stream>>>(Sb, SEQ);

    // out = P @ v = P @ (v^T)^T  (NT, fp32 output)
    gemm_nt<float><<<(SEQ / 128) * (DMODEL / 128), blk, 0, stream>>>(
        Sb, vtb, out, SEQ, DMODEL, SEQ, 1.0f);
}

// Round 3
// 564.627 us; speedup vs baseline: 1.0894x; 1.0177x over previous
//
#include <hip/hip_runtime.h>
#include <hip/hip_bf16.h>
#include <stdint.h>

// SelfAttention: out = softmax((x Wq^T)(x Wk^T)^T / sqrt(D)) (x Wv^T)
// SEQ=8192, D=1024, fp32 in/out. All GEMMs bf16 MFMA (absmax 2.4e-4 vs 1e-3).
// R3: fused QKV GEMM (N=3072) + split-K=2 PV in one dispatch (1024 blocks,
// was 512 = grid-starved at 1.7 blocks/CU) + fp32 add-reduce.
//
// Workspace layout (~232 MB with split, 198 MB fallback):
//   [0)      x_bf16 16MB  (reused as v^T after transpose — x dead by then)
//   [16MB)   Wcat bf16 [3072,1024] 6MB  (Wq|Wk|Wv rows contiguous)
//   [22MB)   qkv bf16 [8192,3072] 48MB  (q=cols 0:1024, k=1024:2048, v=2048:3072)
//   [70MB)   S/P bf16 [8192,8192] 128MB (softmaxed in place)
//   [198MB)  PV split partial fp32 32MB (only if ws_size permits)

#define SEQ 8192
#define DMODEL 1024
#define LOG2E 1.44269504088896340736f
#define GROUP_M 8

typedef __bf16 bf16_t;
typedef __bf16 bf16x8 __attribute__((ext_vector_type(8)));
typedef float f32x4 __attribute__((ext_vector_type(4)));

// ---------------- fp32 -> bf16 convert ----------------
__global__ __launch_bounds__(256)
void convert_f32_bf16(const float* __restrict__ in, bf16_t* __restrict__ out, long n) {
    long i = ((long)blockIdx.x * 256 + threadIdx.x) * 4;
    if (i + 3 < n) {
        const float4 v = *(const float4*)(in + i);
        union { ushort4 u; bf16_t b[4]; } p;
        p.b[0] = (bf16_t)v.x; p.b[1] = (bf16_t)v.y;
        p.b[2] = (bf16_t)v.z; p.b[3] = (bf16_t)v.w;
        *(ushort4*)(out + i) = p.u;
    }
}

// ---------------- fp32 add: out += part ----------------
__global__ __launch_bounds__(256)
void add_f32(float* __restrict__ out, const float* __restrict__ part, long n) {
    long i = ((long)blockIdx.x * 256 + threadIdx.x) * 4;
    if (i + 3 < n) {
        float4 a = *(const float4*)(out + i);
        const float4 b = *(const float4*)(part + i);
        a.x += b.x; a.y += b.y; a.z += b.z; a.w += b.w;
        *(float4*)(out + i) = a;
    }
}

// ---------------- NT GEMM: C[M,N] = alpha * A[M,K] @ B[N,K]^T ----------------
// 128x128 tile, BK=32, 256 threads (4 waves, 2x2), each wave 64x64 via 4x4
// grid of mfma_f32_16x16x32_bf16. global_load_lds width-16 staging.
// Grouped swizzle (GROUP_M row-tiles, col-major inside) for L2/L3 locality.
// Split-K: grid.x = nsplit*nbm*nbn; split sid covers K-range
// [sid*Kps, (sid+1)*Kps), writes to C0 (sid=0) or C1 (sid=1).
template <typename OutT>
__global__ __launch_bounds__(256, 3)
void gemm_nt(const bf16_t* __restrict__ A, const bf16_t* __restrict__ B,
             OutT* __restrict__ C0, OutT* __restrict__ C1,
             int M, int N, int Kps, int lda, int ldb, int ldc, float alpha)
{
    __shared__ bf16_t As[128 * 32];
    __shared__ bf16_t Bs[128 * 32];

    const int tid  = threadIdx.x;
    const int wave = tid >> 6;
    const int lane = tid & 63;

    const int nbm = M >> 7, nbn = N >> 7;
    const int tiles = nbm * nbn;
    int bid = blockIdx.x;
    const int sid = bid / tiles;        // split-K id
    bid -= sid * tiles;
    const long kbase = (long)sid * Kps;
    OutT* __restrict__ C = sid ? C1 : C0;

    // grouped swizzle
    const int per_group = GROUP_M * nbn;
    const int gid   = bid / per_group;
    const int rem   = bid - gid * per_group;
    const int first = gid * GROUP_M;
    const int gsz   = min(nbm - first, GROUP_M);
    const int bm    = first + rem % gsz;
    const int bn    = rem / gsz;
    const long row0 = (long)bm * 128;
    const long col0 = (long)bn * 128;

    const int wm = (wave >> 1) * 64;   // wave's 64x64 sub-tile
    const int wn = (wave & 1) * 64;
    const int lr = lane & 15;          // fragment non-K index
    const int lq = lane >> 4;          // quad 0..3 -> k-chunk / row group

    f32x4 acc[4][4] = {};

    for (int k0 = 0; k0 < Kps; k0 += 32) {
        // Stage A,B 128x32 tiles: 512 chunks of 16B; chunk c -> row c>>2,
        // col-chunk c&3. Wave w issue i covers chunks [i*256+w*64, +64).
        #pragma unroll
        for (int i = 0; i < 2; ++i) {
            const int cbase = i * 256 + wave * 64;
            const int c = cbase + lane;
            const int r = c >> 2, cc = c & 3;
            const bf16_t* ga = A + (row0 + r) * (long)lda + kbase + k0 + cc * 8;
            const bf16_t* gb = B + (col0 + r) * (long)ldb + kbase + k0 + cc * 8;
            __builtin_amdgcn_global_load_lds(
                (const __attribute__((address_space(1))) uint32_t*)ga,
                (__attribute__((address_space(3))) uint32_t*)(As + (long)cbase * 8),
                16, 0, 0);
            __builtin_amdgcn_global_load_lds(
                (const __attribute__((address_space(1))) uint32_t*)gb,
                (__attribute__((address_space(3))) uint32_t*)(Bs + (long)cbase * 8),
                16, 0, 0);
        }
        __syncthreads();

        bf16x8 af[4], bfr[4];
        #pragma unroll
        for (int mi = 0; mi < 4; ++mi)
            af[mi] = *(const bf16x8*)(As + (wm + mi * 16 + lr) * 32 + lq * 8);
        #pragma unroll
        for (int ni = 0; ni < 4; ++ni)
            bfr[ni] = *(const bf16x8*)(Bs + (wn + ni * 16 + lr) * 32 + lq * 8);

        #pragma unroll
        for (int mi = 0; mi < 4; ++mi)
            #pragma unroll
            for (int ni = 0; ni < 4; ++ni)
                acc[mi][ni] = __builtin_amdgcn_mfma_f32_16x16x32_bf16(
                    af[mi], bfr[ni], acc[mi][ni], 0, 0, 0);
        __syncthreads();
    }

    // Epilogue: C/D layout col=lane&15, row=(lane>>4)*4+reg  [m89/m91 verified]
    #pragma unroll
    for (int mi = 0; mi < 4; ++mi)
        #pragma unroll
        for (int ni = 0; ni < 4; ++ni)
            #pragma unroll
            for (int rg = 0; rg < 4; ++rg) {
                const long r = row0 + wm + mi * 16 + lq * 4 + rg;
                const long c = col0 + wn + ni * 16 + lr;
                C[r * (long)ldc + c] = (OutT)(alpha * acc[mi][ni][rg]);
            }
}

// ---------------- bf16 transpose (strided in), v -> v^T ----------------
__global__ __launch_bounds__(256)
void transpose_bf16(const bf16_t* __restrict__ in, bf16_t* __restrict__ out,
                    int R, int ldin, int ldout)
{
    __shared__ bf16_t tile[32][33];
    const int tx = threadIdx.x & 31;
    const int ty = threadIdx.x >> 5;   // 0..7
    const int c0 = blockIdx.x * 32;
    const int r0 = blockIdx.y * 32;
    #pragma unroll
    for (int j = 0; j < 32; j += 8)
        tile[ty + j][tx] = in[(long)(r0 + ty + j) * ldin + c0 + tx];
    __syncthreads();
    #pragma unroll
    for (int j = 0; j < 32; j += 8)
        out[(long)(c0 + ty + j) * ldout + r0 + tx] = tile[tx][ty + j];
}

// ---------------- row softmax over bf16 [SEQ, SEQ], in place ----------------
__global__ __launch_bounds__(256)
void softmax_rows(bf16_t* __restrict__ S, int n)
{
    const long row = blockIdx.x;
    bf16_t* p = S + row * (long)n;
    const int tid = threadIdx.x;
    const int wave = tid >> 6, lane = tid & 63;
    __shared__ float red[4];

    float v[32];
    #pragma unroll
    for (int j = 0; j < 4; ++j) {
        bf16x8 x = *(const bf16x8*)(p + ((long)(j * 256 + tid)) * 8);
        #pragma unroll
        for (int e = 0; e < 8; ++e) v[j * 8 + e] = (float)x[e];
    }
    float m = -3.4e38f;
    #pragma unroll
    for (int i = 0; i < 32; ++i) m = fmaxf(m, v[i]);
    #pragma unroll
    for (int off = 32; off > 0; off >>= 1) m = fmaxf(m, __shfl_xor(m, off));
    if (lane == 0) red[wave] = m;
    __syncthreads();
    m = fmaxf(fmaxf(red[0], red[1]), fmaxf(red[2], red[3]));
    __syncthreads();

    float s = 0.f;
    #pragma unroll
    for (int i = 0; i < 32; ++i) { v[i] = exp2f((v[i] - m) * LOG2E); s += v[i]; }
    #pragma unroll
    for (int off = 32; off > 0; off >>= 1) s += __shfl_xor(s, off);
    if (lane == 0) red[wave] = s;
    __syncthreads();
    s = red[0] + red[1] + red[2] + red[3];
    const float inv = 1.f / s;

    #pragma unroll
    for (int j = 0; j < 4; ++j) {
        bf16x8 x;
        #pragma unroll
        for (int e = 0; e < 8; ++e) x[e] = (bf16_t)(v[j * 8 + e] * inv);
        *(bf16x8*)(p + ((long)(j * 256 + tid)) * 8) = x;
    }
}

extern "C" void kernel_launch(void* const* d_in, const int* in_sizes, int n_in,
                              void* d_out, int out_size, void* d_ws, size_t ws_size,
                              hipStream_t stream)
{
    const float* x  = (const float*)d_in[0];
    const float* Wq = (const float*)d_in[1];
    const float* Wk = (const float*)d_in[2];
    const float* Wv = (const float*)d_in[3];
    float* out = (float*)d_out;

    char* ws = (char*)d_ws;
    const long XN = (long)SEQ * DMODEL;     // 8,388,608
    const long WN = (long)DMODEL * DMODEL;  // 1,048,576
    const long SN = (long)SEQ * SEQ;        // 67,108,864

    bf16_t* xb   = (bf16_t*)ws;                         // 16MB
    bf16_t* wcat = (bf16_t*)(ws + XN * 2);              // 6MB [3072,1024]
    bf16_t* qkv  = (bf16_t*)(ws + XN * 2 + WN * 6);     // 48MB [8192,3072]
    bf16_t* Sb   = (bf16_t*)(ws + XN * 2 + WN * 6 + XN * 6);  // 128MB
    float*  pvp  = (float*)(ws + XN * 2 + WN * 6 + XN * 6 + SN * 2);  // 32MB
    bf16_t* vtb  = xb;  // v^T overlays x_bf16 (x dead after QKV GEMM)

    const size_t need_split = (size_t)(XN * 2 + WN * 6 + XN * 6 + SN * 2) + XN * 4;
    const bool use_split = ws_size >= need_split;

    convert_f32_bf16<<<(int)(XN / 4 / 256), 256, 0, stream>>>(x,  xb, XN);
    convert_f32_bf16<<<(int)(WN / 4 / 256), 256, 0, stream>>>(Wq, wcat,          WN);
    convert_f32_bf16<<<(int)(WN / 4 / 256), 256, 0, stream>>>(Wk, wcat + WN,     WN);
    convert_f32_bf16<<<(int)(WN / 4 / 256), 256, 0, stream>>>(Wv, wcat + 2 * WN, WN);

    dim3 blk(256);
    // qkv = x @ Wcat^T   [8192,3072]
    gemm_nt<bf16_t><<<(SEQ / 128) * (3 * DMODEL / 128), blk, 0, stream>>>(
        xb, wcat, qkv, qkv, SEQ, 3 * DMODEL, DMODEL,
        DMODEL, DMODEL, 3 * DMODEL, 1.0f);

    bf16_t* qb = qkv;
    bf16_t* kb = qkv + DMODEL;
    bf16_t* vb = qkv + 2 * DMODEL;

    // v^T for the PV GEMM (writes over dead x_bf16)
    transpose_bf16<<<dim3(DMODEL / 32, SEQ / 32), blk, 0, stream>>>(
        vb, vtb, SEQ, 3 * DMODEL, SEQ);

    // S = (q @ k^T) * 1/sqrt(1024)
    gemm_nt<bf16_t><<<(SEQ / 128) * (SEQ / 128), blk, 0, stream>>>(
        qb, kb, Sb, Sb, SEQ, SEQ, DMODEL,
        3 * DMODEL, 3 * DMODEL, SEQ, 0.03125f);

    softmax_rows<<<SEQ, blk, 0, stream>>>(Sb, SEQ);

    // out = P @ (v^T)^T  (NT, fp32 output). Split-K=2 if ws allows.
    if (use_split) {
        gemm_nt<float><<<2 * (SEQ / 128) * (DMODEL / 128), blk, 0, stream>>>(
            Sb, vtb, out, pvp, SEQ, DMODEL, SEQ / 2,
            SEQ, SEQ, DMODEL, 1.0f);
        add_f32<<<(int)(XN / 4 / 256), 256, 0, stream>>>(out, pvp, XN);
    } else {
        gemm_nt<float><<<(SEQ / 128) * (DMODEL / 128), blk, 0, stream>>>(
            Sb, vtb, out, out, SEQ, DMODEL, SEQ,
            SEQ, SEQ, DMODEL, 1.0f);
    }
}

// Round 4
// 545.097 us; speedup vs baseline: 1.1284x; 1.0358x over previous
//
#include <hip/hip_runtime.h>
#include <hip/hip_bf16.h>
#include <stdint.h>

// SelfAttention: out = softmax((x Wq^T)(x Wk^T)^T / sqrt(D)) (x Wv^T)
// SEQ=8192, D=1024, fp32 in/out. All GEMMs bf16 MFMA (absmax 2.4e-4 vs 1e-3).
// R4: fused QKV GEMM now writes COMPACT q,k,v buffers (epilogue de-interleave).
// R3's strided q/k (lda=3072, stride 6144B = 3*2^11) aliased L2 sets: S-GEMM
// FETCH 150->498MB, dur 194->205us. Compact restores R2's L2 behavior.
//
// Workspace (~230 MB): x_bf16 16 | Wcat 6 | q 16 | k 16 | v 16 | S 128 | pv 32

#define SEQ 8192
#define DMODEL 1024
#define LOG2E 1.44269504088896340736f
#define GROUP_M 8

typedef __bf16 bf16_t;
typedef __bf16 bf16x8 __attribute__((ext_vector_type(8)));
typedef float f32x4 __attribute__((ext_vector_type(4)));

// ---------------- fp32 -> bf16 convert ----------------
__global__ __launch_bounds__(256)
void convert_f32_bf16(const float* __restrict__ in, bf16_t* __restrict__ out, long n) {
    long i = ((long)blockIdx.x * 256 + threadIdx.x) * 4;
    if (i + 3 < n) {
        const float4 v = *(const float4*)(in + i);
        union { ushort4 u; bf16_t b[4]; } p;
        p.b[0] = (bf16_t)v.x; p.b[1] = (bf16_t)v.y;
        p.b[2] = (bf16_t)v.z; p.b[3] = (bf16_t)v.w;
        *(ushort4*)(out + i) = p.u;
    }
}

// ---------------- fp32 add: out += part ----------------
__global__ __launch_bounds__(256)
void add_f32(float* __restrict__ out, const float* __restrict__ part, long n) {
    long i = ((long)blockIdx.x * 256 + threadIdx.x) * 4;
    if (i + 3 < n) {
        float4 a = *(const float4*)(out + i);
        const float4 b = *(const float4*)(part + i);
        a.x += b.x; a.y += b.y; a.z += b.z; a.w += b.w;
        *(float4*)(out + i) = a;
    }
}

// ---------------- NT GEMM: C[M,N] = alpha * A[M,K] @ B[N,K]^T ----------------
// 128x128 tile, BK=32, 256 threads (4 waves, 2x2), each wave 64x64 via 4x4
// grid of mfma_f32_16x16x32_bf16. global_load_lds width-16 staging.
// Grouped swizzle (GROUP_M row-tiles, col-major inside) for L2/L3 locality.
// Split-K: grid.x = nsplit*nbm*nbn; split sid covers [sid*Kps,(sid+1)*Kps),
// writes C0 (sid=0) or C1 (sid=1).
// De-interleave: element (r,c) stored at C[(c>>cshift)*plane + r*ldc + (c&mask)]
// (cshift=30/plane=0 for normal GEMMs; cshift=10/plane=SEQ*DMODEL for QKV).
template <typename OutT>
__global__ __launch_bounds__(256, 3)
void gemm_nt(const bf16_t* __restrict__ A, const bf16_t* __restrict__ B,
             OutT* __restrict__ C0, OutT* __restrict__ C1,
             int M, int N, int Kps, int lda, int ldb, int ldc,
             long plane, int cshift, float alpha)
{
    __shared__ bf16_t As[128 * 32];
    __shared__ bf16_t Bs[128 * 32];

    const int tid  = threadIdx.x;
    const int wave = tid >> 6;
    const int lane = tid & 63;

    const int nbm = M >> 7, nbn = N >> 7;
    const int tiles = nbm * nbn;
    int bid = blockIdx.x;
    const int sid = bid / tiles;        // split-K id
    bid -= sid * tiles;
    const long kbase = (long)sid * Kps;
    OutT* __restrict__ C = sid ? C1 : C0;

    // grouped swizzle
    const int per_group = GROUP_M * nbn;
    const int gid   = bid / per_group;
    const int rem   = bid - gid * per_group;
    const int first = gid * GROUP_M;
    const int gsz   = min(nbm - first, GROUP_M);
    const int bm    = first + rem % gsz;
    const int bn    = rem / gsz;
    const long row0 = (long)bm * 128;
    const long col0 = (long)bn * 128;

    const int wm = (wave >> 1) * 64;   // wave's 64x64 sub-tile
    const int wn = (wave & 1) * 64;
    const int lr = lane & 15;          // fragment non-K index
    const int lq = lane >> 4;          // quad 0..3 -> k-chunk / row group

    f32x4 acc[4][4] = {};

    for (int k0 = 0; k0 < Kps; k0 += 32) {
        // Stage A,B 128x32 tiles: 512 chunks of 16B; chunk c -> row c>>2,
        // col-chunk c&3. Wave w issue i covers chunks [i*256+w*64, +64).
        #pragma unroll
        for (int i = 0; i < 2; ++i) {
            const int cbase = i * 256 + wave * 64;
            const int c = cbase + lane;
            const int r = c >> 2, cc = c & 3;
            const bf16_t* ga = A + (row0 + r) * (long)lda + kbase + k0 + cc * 8;
            const bf16_t* gb = B + (col0 + r) * (long)ldb + kbase + k0 + cc * 8;
            __builtin_amdgcn_global_load_lds(
                (const __attribute__((address_space(1))) uint32_t*)ga,
                (__attribute__((address_space(3))) uint32_t*)(As + (long)cbase * 8),
                16, 0, 0);
            __builtin_amdgcn_global_load_lds(
                (const __attribute__((address_space(1))) uint32_t*)gb,
                (__attribute__((address_space(3))) uint32_t*)(Bs + (long)cbase * 8),
                16, 0, 0);
        }
        __syncthreads();

        bf16x8 af[4], bfr[4];
        #pragma unroll
        for (int mi = 0; mi < 4; ++mi)
            af[mi] = *(const bf16x8*)(As + (wm + mi * 16 + lr) * 32 + lq * 8);
        #pragma unroll
        for (int ni = 0; ni < 4; ++ni)
            bfr[ni] = *(const bf16x8*)(Bs + (wn + ni * 16 + lr) * 32 + lq * 8);

        #pragma unroll
        for (int mi = 0; mi < 4; ++mi)
            #pragma unroll
            for (int ni = 0; ni < 4; ++ni)
                acc[mi][ni] = __builtin_amdgcn_mfma_f32_16x16x32_bf16(
                    af[mi], bfr[ni], acc[mi][ni], 0, 0, 0);
        __syncthreads();
    }

    // Epilogue: C/D layout col=lane&15, row=(lane>>4)*4+reg  [m89/m91 verified]
    OutT* __restrict__ Cb = C + (col0 >> cshift) * plane;
    const int ccol0 = (int)(col0 & (((long)1 << cshift) - 1));
    #pragma unroll
    for (int mi = 0; mi < 4; ++mi)
        #pragma unroll
        for (int ni = 0; ni < 4; ++ni)
            #pragma unroll
            for (int rg = 0; rg < 4; ++rg) {
                const long r = row0 + wm + mi * 16 + lq * 4 + rg;
                const int  c = ccol0 + wn + ni * 16 + lr;
                Cb[r * (long)ldc + c] = (OutT)(alpha * acc[mi][ni][rg]);
            }
}

// ---------------- bf16 transpose (strided in), v -> v^T ----------------
__global__ __launch_bounds__(256)
void transpose_bf16(const bf16_t* __restrict__ in, bf16_t* __restrict__ out,
                    int R, int ldin, int ldout)
{
    __shared__ bf16_t tile[32][33];
    const int tx = threadIdx.x & 31;
    const int ty = threadIdx.x >> 5;   // 0..7
    const int c0 = blockIdx.x * 32;
    const int r0 = blockIdx.y * 32;
    #pragma unroll
    for (int j = 0; j < 32; j += 8)
        tile[ty + j][tx] = in[(long)(r0 + ty + j) * ldin + c0 + tx];
    __syncthreads();
    #pragma unroll
    for (int j = 0; j < 32; j += 8)
        out[(long)(c0 + ty + j) * ldout + r0 + tx] = tile[tx][ty + j];
}

// ---------------- row softmax over bf16 [SEQ, SEQ], in place ----------------
__global__ __launch_bounds__(256)
void softmax_rows(bf16_t* __restrict__ S, int n)
{
    const long row = blockIdx.x;
    bf16_t* p = S + row * (long)n;
    const int tid = threadIdx.x;
    const int wave = tid >> 6, lane = tid & 63;
    __shared__ float red[4];

    float v[32];
    #pragma unroll
    for (int j = 0; j < 4; ++j) {
        bf16x8 x = *(const bf16x8*)(p + ((long)(j * 256 + tid)) * 8);
        #pragma unroll
        for (int e = 0; e < 8; ++e) v[j * 8 + e] = (float)x[e];
    }
    float m = -3.4e38f;
    #pragma unroll
    for (int i = 0; i < 32; ++i) m = fmaxf(m, v[i]);
    #pragma unroll
    for (int off = 32; off > 0; off >>= 1) m = fmaxf(m, __shfl_xor(m, off));
    if (lane == 0) red[wave] = m;
    __syncthreads();
    m = fmaxf(fmaxf(red[0], red[1]), fmaxf(red[2], red[3]));
    __syncthreads();

    float s = 0.f;
    #pragma unroll
    for (int i = 0; i < 32; ++i) { v[i] = exp2f((v[i] - m) * LOG2E); s += v[i]; }
    #pragma unroll
    for (int off = 32; off > 0; off >>= 1) s += __shfl_xor(s, off);
    if (lane == 0) red[wave] = s;
    __syncthreads();
    s = red[0] + red[1] + red[2] + red[3];
    const float inv = 1.f / s;

    #pragma unroll
    for (int j = 0; j < 4; ++j) {
        bf16x8 x;
        #pragma unroll
        for (int e = 0; e < 8; ++e) x[e] = (bf16_t)(v[j * 8 + e] * inv);
        *(bf16x8*)(p + ((long)(j * 256 + tid)) * 8) = x;
    }
}

extern "C" void kernel_launch(void* const* d_in, const int* in_sizes, int n_in,
                              void* d_out, int out_size, void* d_ws, size_t ws_size,
                              hipStream_t stream)
{
    const float* x  = (const float*)d_in[0];
    const float* Wq = (const float*)d_in[1];
    const float* Wk = (const float*)d_in[2];
    const float* Wv = (const float*)d_in[3];
    float* out = (float*)d_out;

    char* ws = (char*)d_ws;
    const long XN = (long)SEQ * DMODEL;     // 8,388,608
    const long WN = (long)DMODEL * DMODEL;  // 1,048,576
    const long SN = (long)SEQ * SEQ;        // 67,108,864

    bf16_t* xb   = (bf16_t*)ws;                              // 16MB
    bf16_t* wcat = (bf16_t*)(ws + XN * 2);                   // 6MB [3072,1024]
    bf16_t* qb   = (bf16_t*)(ws + XN * 2 + WN * 6);          // 16MB compact
    bf16_t* kb   = qb + XN;                                  // 16MB compact
    bf16_t* vb   = qb + 2 * XN;                              // 16MB compact
    bf16_t* Sb   = (bf16_t*)(ws + XN * 2 + WN * 6 + XN * 6); // 128MB
    float*  pvp  = (float*)(ws + XN * 2 + WN * 6 + XN * 6 + SN * 2); // 32MB
    bf16_t* vtb  = xb;  // v^T overlays x_bf16 (x dead after QKV GEMM)

    const size_t need_split = (size_t)(XN * 2 + WN * 6 + XN * 6 + SN * 2) + XN * 4;
    const bool use_split = ws_size >= need_split;

    convert_f32_bf16<<<(int)(XN / 4 / 256), 256, 0, stream>>>(x,  xb, XN);
    convert_f32_bf16<<<(int)(WN / 4 / 256), 256, 0, stream>>>(Wq, wcat,          WN);
    convert_f32_bf16<<<(int)(WN / 4 / 256), 256, 0, stream>>>(Wk, wcat + WN,     WN);
    convert_f32_bf16<<<(int)(WN / 4 / 256), 256, 0, stream>>>(Wv, wcat + 2 * WN, WN);

    dim3 blk(256);
    // qkv = x @ Wcat^T, de-interleaved into compact q|k|v (plane=XN, cshift=10)
    gemm_nt<bf16_t><<<(SEQ / 128) * (3 * DMODEL / 128), blk, 0, stream>>>(
        xb, wcat, qb, qb, SEQ, 3 * DMODEL, DMODEL,
        DMODEL, DMODEL, DMODEL, XN, 10, 1.0f);

    // v^T for the PV GEMM (writes over dead x_bf16)
    transpose_bf16<<<dim3(DMODEL / 32, SEQ / 32), blk, 0, stream>>>(
        vb, vtb, SEQ, DMODEL, SEQ);

    // S = (q @ k^T) * 1/sqrt(1024)  — compact q,k (lda=ldb=1024)
    gemm_nt<bf16_t><<<(SEQ / 128) * (SEQ / 128), blk, 0, stream>>>(
        qb, kb, Sb, Sb, SEQ, SEQ, DMODEL,
        DMODEL, DMODEL, SEQ, 0, 30, 0.03125f);

    softmax_rows<<<SEQ, blk, 0, stream>>>(Sb, SEQ);

    // out = P @ (v^T)^T  (NT, fp32 output). Split-K=2 if ws allows.
    if (use_split) {
        gemm_nt<float><<<2 * (SEQ / 128) * (DMODEL / 128), blk, 0, stream>>>(
            Sb, vtb, out, pvp, SEQ, DMODEL, SEQ / 2,
            SEQ, SEQ, DMODEL, 0, 30, 1.0f);
        add_f32<<<(int)(XN / 4 / 256), 256, 0, stream>>>(out, pvp, XN);
    } else {
        gemm_nt<float><<<(SEQ / 128) * (DMODEL / 128), blk, 0, stream>>>(
            Sb, vtb, out, out, SEQ, DMODEL, SEQ,
            SEQ, SEQ, DMODEL, 0, 30, 1.0f);
    }
}